// Round 1
// baseline (306.896 us; speedup 1.0000x reference)
//
#include <hip/hip_runtime.h>
#include <math.h>

#define N_ 64
#define C_ 8
#define T_ 300
#define V_ 17
#define M_ 12
#define EPSF 1e-6f
#define TAUF 0.35f

// x shape (N,C,T,V,M), strides: C:61200, T:204, V:12, M:1
// ws layout (floats): pos[64*36] (n,d,m) | s[64*12] (n,m) | A[64*144] (n,u,v)

// ---------------- Kernel 1: reduce pos (hip-root mean over T) and s (ball score mean over T,V)
__global__ __launch_bounds__(256) void k_reduce(const float* __restrict__ x,
                                                float* __restrict__ ws_pos,
                                                float* __restrict__ ws_s) {
    const int n = blockIdx.x;
    const int tid = threadIdx.x;
    __shared__ float pos_acc[36];
    __shared__ float s_acc[12];
    if (tid < 36) pos_acc[tid] = 0.f;
    if (tid < 12) s_acc[tid] = 0.f;
    __syncthreads();

    // ---- pos part: e = t*12+m over [0,3600), d in 0..2
    {
        float a[3][3];
        #pragma unroll
        for (int d = 0; d < 3; ++d)
            #pragma unroll
            for (int ph = 0; ph < 3; ++ph) a[d][ph] = 0.f;
        for (int e = tid; e < 3600; e += 768) {
            #pragma unroll
            for (int ph = 0; ph < 3; ++ph) {
                int ee = e + ph * 256;
                if (ee < 3600) {
                    int t = ee / 12, m = ee % 12;
                    #pragma unroll
                    for (int d = 0; d < 3; ++d) {
                        const float* xb = x + ((size_t)(n * C_ + d) * T_ + t) * (V_ * M_);
                        a[d][ph] += xb[132 + m] + xb[144 + m];  // v=11, v=12
                    }
                }
            }
        }
        int m0 = tid % 12;
        #pragma unroll
        for (int ph = 0; ph < 3; ++ph) {
            int m = (m0 + 4 * ph) % 12;   // stride 256 == 4 (mod 12), period 3
            #pragma unroll
            for (int d = 0; d < 3; ++d) atomicAdd(&pos_acc[d * 12 + m], a[d][ph]);
        }
    }

    // ---- s part: channel 3 full slice, 61200 elements, m = e%12
    {
        float a0 = 0.f, a1 = 0.f, a2 = 0.f;
        const float* xs = x + (size_t)(n * C_ + 3) * T_ * V_ * M_;
        for (int e = tid; e < 61200; e += 768) {
            a0 += xs[e];
            if (e + 256 < 61200) a1 += xs[e + 256];
            if (e + 512 < 61200) a2 += xs[e + 512];
        }
        int m0 = tid % 12;
        atomicAdd(&s_acc[m0], a0);
        atomicAdd(&s_acc[(m0 + 4) % 12], a1);
        atomicAdd(&s_acc[(m0 + 8) % 12], a2);
    }
    __syncthreads();
    if (tid < 36) ws_pos[n * 36 + tid] = pos_acc[tid] * (0.5f / (float)T_);
    if (tid < 12) ws_s[n * 12 + tid] = s_acc[tid] * (1.f / (float)(T_ * V_));
}

// ---------------- Kernel 2: build fused adjacency A (N,12,12)
__global__ __launch_bounds__(64) void k_adj(const float* __restrict__ ws_pos,
                                            const float* __restrict__ ws_s,
                                            const float* __restrict__ alpha_logits,
                                            float* __restrict__ ws_A) {
    const int n = blockIdx.x;
    const int tid = threadIdx.x;
    __shared__ float posx[12], posy[12], posz[12];
    __shared__ float dist[144];
    __shared__ int ord[60];
    __shared__ float p_s[12];
    __shared__ float alpha_s[4];
    __shared__ float w_s;

    if (tid < 12) {
        posx[tid] = ws_pos[n * 36 + 0 * 12 + tid];
        posy[tid] = ws_pos[n * 36 + 1 * 12 + tid];
        posz[tid] = ws_pos[n * 36 + 2 * 12 + tid];
    }
    if (tid == 0) {
        float l0 = alpha_logits[0], l1 = alpha_logits[1], l2 = alpha_logits[2], l3 = alpha_logits[3];
        float mx = fmaxf(fmaxf(l0, l1), fmaxf(l2, l3));
        float e0 = expf(l0 - mx), e1 = expf(l1 - mx), e2 = expf(l2 - mx), e3 = expf(l3 - mx);
        float s = e0 + e1 + e2 + e3;
        alpha_s[0] = e0 / s; alpha_s[1] = e1 / s; alpha_s[2] = e2 / s; alpha_s[3] = e3 / s;
    }
    if (tid == 1) {
        // softmax p over s/tau, plus confidence weight w
        float sv[12];
        float mx = -1e30f;
        #pragma unroll
        for (int m = 0; m < 12; ++m) { sv[m] = ws_s[n * 12 + m] * (1.f / TAUF); mx = fmaxf(mx, sv[m]); }
        float sum = 0.f;
        #pragma unroll
        for (int m = 0; m < 12; ++m) { sv[m] = expf(sv[m] - mx); sum += sv[m]; }
        float maxp = 0.f;
        #pragma unroll
        for (int m = 0; m < 12; ++m) { sv[m] = sv[m] / sum; p_s[m] = sv[m]; maxp = fmaxf(maxp, sv[m]); }
        float w = (maxp - 1.f / 12.f) / (1.f - 1.f / 12.f + EPSF);
        w_s = fminf(fmaxf(w, 0.f), 1.f);
    }
    __syncthreads();

    for (int e = tid; e < 144; e += 64) {
        int i = e / 12, j = e % 12;
        float dx = posx[i] - posx[j], dy = posy[i] - posy[j], dz = posz[i] - posz[j];
        dist[e] = sqrtf(dx * dx + dy * dy + dz * dz);
    }
    __syncthreads();

    // top-5 nearest per row (stable tie-break: smallest index wins, matches lax.top_k)
    if (tid < 12) {
        int i = tid, mask = 0;
        #pragma unroll
        for (int r = 0; r < 5; ++r) {
            float bd = 1e30f; int bj = -1;
            #pragma unroll
            for (int j = 0; j < 12; ++j) {
                if (!((mask >> j) & 1)) {
                    float dd = dist[i * 12 + j];
                    if (dd < bd) { bd = dd; bj = j; }
                }
            }
            ord[i * 5 + r] = bj; mask |= (1 << bj);
        }
    }
    __syncthreads();

    float w = w_s;
    for (int e = tid; e < 144; e += 64) {
        int i = e / 12, j = e % 12;
        int rank = 5;
        #pragma unroll
        for (int r = 4; r >= 0; --r) if (ord[i * 5 + r] == j) rank = r;
        float diag = (i == j) ? 1.f : 0.f;
        // kNN rows always contain self (dist 0) -> row sum == k+1 exactly, so
        // sym_norm(A_k) = A_k / (k+1+eps)
        float aknn = 0.f;
        #pragma unroll
        for (int kk = 0; kk < 4; ++kk) {
            int K = kk + 2;
            float val = ((rank < K) ? 1.f : 0.f) + diag;
            aknn += alpha_s[kk] * val / ((float)(K + 1) + EPSF);
        }
        float pi = p_s[i], pj = p_s[j];
        float di = 12.f * pi + 2.f, dj = 12.f * pj + 2.f;  // ball row sums
        float ab = (pi + pj + diag) * rsqrtf(di + EPSF) * rsqrtf(dj + EPSF);
        ws_A[n * 144 + e] = w * ab + (1.f - w) * aknn;
    }
}

// ---------------- Kernel 3: out = x + scale * (A@root - root), broadcast over V
#define RT 30   // rows (n,c,t) per block; 2400 % 30 == 0
__global__ __launch_bounds__(256) void k_main(const float* __restrict__ x,
                                              const float* __restrict__ ws_A,
                                              const float* __restrict__ lambda_fuse,
                                              const float* __restrict__ tag_gate,
                                              float* __restrict__ out) {
    const int n = blockIdx.y;
    const int r0 = blockIdx.x * RT;   // row index within n, rows = C*T = 2400
    const int tid = threadIdx.x;
    __shared__ float Ash[144];
    __shared__ float root_sh[RT * 12];
    __shared__ float delta_sh[RT * 12];

    if (tid < 144) Ash[tid] = ws_A[n * 144 + tid];
    float scale = tanhf(tag_gate[0]) * lambda_fuse[0];

    const float* xn = x + (size_t)n * 2400 * 204;
    float* on = out + (size_t)n * 2400 * 204;

    for (int e = tid; e < RT * 12; e += 256) {
        int r = e / 12, v = e % 12;
        const float* row = xn + (size_t)(r0 + r) * 204;
        root_sh[e] = 0.5f * (row[132 + v] + row[144 + v]);  // v=11,12 slots
    }
    __syncthreads();
    for (int e = tid; e < RT * 12; e += 256) {
        int r = e / 12, u = e % 12;
        float acc = 0.f;
        #pragma unroll
        for (int v = 0; v < 12; ++v) acc += Ash[u * 12 + v] * root_sh[r * 12 + v];
        delta_sh[e] = scale * (acc - root_sh[e]);
    }
    __syncthreads();

    const float4* x4 = (const float4*)(xn + (size_t)r0 * 204);
    float4* o4 = (float4*)(on + (size_t)r0 * 204);
    for (int f = tid; f < RT * 51; f += 256) {
        int r = f / 51, j = f % 51;
        int m0 = (4 * j) % 12;            // m never wraps inside a float4 (m0 in {0,4,8})
        float4 v = x4[(size_t)r * 51 + j];
        const float* d = &delta_sh[r * 12 + m0];
        v.x += d[0]; v.y += d[1]; v.z += d[2]; v.w += d[3];
        o4[(size_t)r * 51 + j] = v;
    }
}

extern "C" void kernel_launch(void* const* d_in, const int* in_sizes, int n_in,
                              void* d_out, int out_size, void* d_ws, size_t ws_size,
                              hipStream_t stream) {
    const float* x = (const float*)d_in[0];
    const float* alpha_logits = (const float*)d_in[1];
    const float* lambda_fuse = (const float*)d_in[2];
    const float* tag_gate = (const float*)d_in[3];
    float* out = (float*)d_out;

    float* ws = (float*)d_ws;
    float* ws_pos = ws;                 // 64*36
    float* ws_s = ws + 64 * 36;         // 64*12
    float* ws_A = ws + 64 * 36 + 64 * 12; // 64*144

    k_reduce<<<dim3(N_), dim3(256), 0, stream>>>(x, ws_pos, ws_s);
    k_adj<<<dim3(N_), dim3(64), 0, stream>>>(ws_pos, ws_s, alpha_logits, ws_A);
    k_main<<<dim3(2400 / RT, N_), dim3(256), 0, stream>>>(x, ws_A, lambda_fuse, tag_gate, out);
}

// Round 2
// 255.565 us; speedup vs baseline: 1.2009x; 1.2009x over previous
//
#include <hip/hip_runtime.h>
#include <math.h>

#define N_ 64
#define C_ 8
#define T_ 300
#define V_ 17
#define M_ 12
#define EPSF 1e-6f
#define TAUF 0.35f

// x shape (N,C,T,V,M), strides: C:61200, T:204, V:12, M:1
// ws layout (floats): pos_raw[64*36] (n,d,m) | s_raw[64*12] (n,m) | A[64*144] (n,u,v)
// pos_raw/s_raw are UNSCALED sums (scaling applied in k_adj); zeroed by hipMemsetAsync.

#define TSPLIT 10
#define TCH (T_ / TSPLIT)   // 30 t per block

// ---------------- Kernel 1: partial reduce over a t-chunk, global atomic accumulate
__global__ __launch_bounds__(256) void k_reduce(const float* __restrict__ x,
                                                float* __restrict__ ws_pos,
                                                float* __restrict__ ws_s) {
    const int n = blockIdx.x;
    const int t0 = blockIdx.y * TCH;
    const int tid = threadIdx.x;
    __shared__ float pos_acc[36];
    __shared__ float s_acc[12];
    if (tid < 36) pos_acc[tid] = 0.f;
    if (tid < 12) s_acc[tid] = 0.f;
    __syncthreads();

    // ---- s part: channel 3, contiguous chunk of 30 rows = 6120 floats
    {
        const float* xs = x + ((size_t)(n * C_ + 3) * T_ + t0) * 204;
        float a0 = 0.f, a1 = 0.f, a2 = 0.f;
        for (int e = tid; e < TCH * 204; e += 768) {
            a0 += xs[e];
            if (e + 256 < TCH * 204) a1 += xs[e + 256];
            if (e + 512 < TCH * 204) a2 += xs[e + 512];
        }
        // stride 768 ≡ 0 (mod 12): each phase hits a fixed m
        int m0 = tid % 12;
        atomicAdd(&s_acc[m0], a0);
        atomicAdd(&s_acc[(m0 + 4) % 12], a1);
        atomicAdd(&s_acc[(m0 + 8) % 12], a2);
    }

    // ---- pos part: d in 0..2, t in chunk, 24 floats (v=11,12) per (d,t) -> 2160 elems
    for (int e = tid; e < 3 * TCH * 24; e += 256) {
        int d = e / (TCH * 24);
        int rem = e % (TCH * 24);
        int tt = rem / 24, j = rem % 24;
        float val = x[((size_t)(n * C_ + d) * T_ + t0 + tt) * 204 + 132 + j];
        atomicAdd(&pos_acc[d * 12 + (j % 12)], val);
    }
    __syncthreads();

    if (tid < 36) atomicAdd(&ws_pos[n * 36 + tid], pos_acc[tid]);
    if (tid < 12) atomicAdd(&ws_s[n * 12 + tid], s_acc[tid]);
}

// ---------------- Kernel 2: build fused adjacency A (N,12,12) from raw sums
__global__ __launch_bounds__(64) void k_adj(const float* __restrict__ ws_pos,
                                            const float* __restrict__ ws_s,
                                            const float* __restrict__ alpha_logits,
                                            float* __restrict__ ws_A) {
    const int n = blockIdx.x;
    const int tid = threadIdx.x;
    __shared__ float posx[12], posy[12], posz[12];
    __shared__ float dist[144];
    __shared__ int ord[60];
    __shared__ float p_s[12];
    __shared__ float alpha_s[4];
    __shared__ float w_s;

    const float PSC = 0.5f / (float)T_;          // pos = raw * 0.5/T
    if (tid < 12) {
        posx[tid] = ws_pos[n * 36 + 0 * 12 + tid] * PSC;
        posy[tid] = ws_pos[n * 36 + 1 * 12 + tid] * PSC;
        posz[tid] = ws_pos[n * 36 + 2 * 12 + tid] * PSC;
    }
    if (tid == 0) {
        float l0 = alpha_logits[0], l1 = alpha_logits[1], l2 = alpha_logits[2], l3 = alpha_logits[3];
        float mx = fmaxf(fmaxf(l0, l1), fmaxf(l2, l3));
        float e0 = expf(l0 - mx), e1 = expf(l1 - mx), e2 = expf(l2 - mx), e3 = expf(l3 - mx);
        float s = e0 + e1 + e2 + e3;
        alpha_s[0] = e0 / s; alpha_s[1] = e1 / s; alpha_s[2] = e2 / s; alpha_s[3] = e3 / s;
    }
    if (tid == 1) {
        const float SSC = 1.f / (float)(T_ * V_);  // s = raw / (T*V)
        float sv[12];
        float mx = -1e30f;
        #pragma unroll
        for (int m = 0; m < 12; ++m) { sv[m] = (ws_s[n * 12 + m] * SSC) * (1.f / TAUF); mx = fmaxf(mx, sv[m]); }
        float sum = 0.f;
        #pragma unroll
        for (int m = 0; m < 12; ++m) { sv[m] = expf(sv[m] - mx); sum += sv[m]; }
        float maxp = 0.f;
        #pragma unroll
        for (int m = 0; m < 12; ++m) { sv[m] = sv[m] / sum; p_s[m] = sv[m]; maxp = fmaxf(maxp, sv[m]); }
        float w = (maxp - 1.f / 12.f) / (1.f - 1.f / 12.f + EPSF);
        w_s = fminf(fmaxf(w, 0.f), 1.f);
    }
    __syncthreads();

    for (int e = tid; e < 144; e += 64) {
        int i = e / 12, j = e % 12;
        float dx = posx[i] - posx[j], dy = posy[i] - posy[j], dz = posz[i] - posz[j];
        dist[e] = sqrtf(dx * dx + dy * dy + dz * dz);
    }
    __syncthreads();

    // top-5 nearest per row (stable tie-break: smallest index wins, matches lax.top_k)
    if (tid < 12) {
        int i = tid, mask = 0;
        #pragma unroll
        for (int r = 0; r < 5; ++r) {
            float bd = 1e30f; int bj = -1;
            #pragma unroll
            for (int j = 0; j < 12; ++j) {
                if (!((mask >> j) & 1)) {
                    float dd = dist[i * 12 + j];
                    if (dd < bd) { bd = dd; bj = j; }
                }
            }
            ord[i * 5 + r] = bj; mask |= (1 << bj);
        }
    }
    __syncthreads();

    float w = w_s;
    for (int e = tid; e < 144; e += 64) {
        int i = e / 12, j = e % 12;
        int rank = 5;
        #pragma unroll
        for (int r = 4; r >= 0; --r) if (ord[i * 5 + r] == j) rank = r;
        float diag = (i == j) ? 1.f : 0.f;
        // kNN rows always contain self (dist 0) -> row sum == k+1 exactly, so
        // sym_norm(A_k) = A_k / (k+1+eps)
        float aknn = 0.f;
        #pragma unroll
        for (int kk = 0; kk < 4; ++kk) {
            int K = kk + 2;
            float val = ((rank < K) ? 1.f : 0.f) + diag;
            aknn += alpha_s[kk] * val / ((float)(K + 1) + EPSF);
        }
        float pi = p_s[i], pj = p_s[j];
        float di = 12.f * pi + 2.f, dj = 12.f * pj + 2.f;  // ball row sums
        float ab = (pi + pj + diag) * rsqrtf(di + EPSF) * rsqrtf(dj + EPSF);
        ws_A[n * 144 + e] = w * ab + (1.f - w) * aknn;
    }
}

// ---------------- Kernel 3: out = x + scale * (A@root - root), broadcast over V
#define RT 30   // rows (c,t) per block; 2400 % 30 == 0
__global__ __launch_bounds__(256) void k_main(const float* __restrict__ x,
                                              const float* __restrict__ ws_A,
                                              const float* __restrict__ lambda_fuse,
                                              const float* __restrict__ tag_gate,
                                              float* __restrict__ out) {
    const int n = blockIdx.y;
    const int r0 = blockIdx.x * RT;   // row index within n, rows = C*T = 2400
    const int tid = threadIdx.x;
    __shared__ float Ash[144];
    __shared__ float root_sh[RT * 12];
    __shared__ float delta_sh[RT * 12];

    if (tid < 144) Ash[tid] = ws_A[n * 144 + tid];
    float scale = tanhf(tag_gate[0]) * lambda_fuse[0];

    const float* xn = x + (size_t)n * 2400 * 204;
    float* on = out + (size_t)n * 2400 * 204;

    for (int e = tid; e < RT * 12; e += 256) {
        int r = e / 12, v = e % 12;
        const float* row = xn + (size_t)(r0 + r) * 204;
        root_sh[e] = 0.5f * (row[132 + v] + row[144 + v]);  // v=11,12 slots
    }
    __syncthreads();
    for (int e = tid; e < RT * 12; e += 256) {
        int r = e / 12, u = e % 12;
        float acc = 0.f;
        #pragma unroll
        for (int v = 0; v < 12; ++v) acc += Ash[u * 12 + v] * root_sh[r * 12 + v];
        delta_sh[e] = scale * (acc - root_sh[e]);
    }
    __syncthreads();

    const float4* x4 = (const float4*)(xn + (size_t)r0 * 204);
    float4* o4 = (float4*)(on + (size_t)r0 * 204);
    for (int f = tid; f < RT * 51; f += 256) {
        int r = f / 51, j = f % 51;
        int m0 = (4 * j) % 12;            // m never wraps inside a float4 (m0 in {0,4,8})
        float4 v = x4[(size_t)r * 51 + j];
        const float* d = &delta_sh[r * 12 + m0];
        v.x += d[0]; v.y += d[1]; v.z += d[2]; v.w += d[3];
        o4[(size_t)r * 51 + j] = v;
    }
}

extern "C" void kernel_launch(void* const* d_in, const int* in_sizes, int n_in,
                              void* d_out, int out_size, void* d_ws, size_t ws_size,
                              hipStream_t stream) {
    const float* x = (const float*)d_in[0];
    const float* alpha_logits = (const float*)d_in[1];
    const float* lambda_fuse = (const float*)d_in[2];
    const float* tag_gate = (const float*)d_in[3];
    float* out = (float*)d_out;

    float* ws = (float*)d_ws;
    float* ws_pos = ws;                   // 64*36 raw sums
    float* ws_s = ws + 64 * 36;           // 64*12 raw sums
    float* ws_A = ws + 64 * 48;           // 64*144

    // zero the atomic accumulators (12 KB)
    hipMemsetAsync(ws, 0, (size_t)(64 * 48) * sizeof(float), stream);

    k_reduce<<<dim3(N_, TSPLIT), dim3(256), 0, stream>>>(x, ws_pos, ws_s);
    k_adj<<<dim3(N_), dim3(64), 0, stream>>>(ws_pos, ws_s, alpha_logits, ws_A);
    k_main<<<dim3(2400 / RT, N_), dim3(256), 0, stream>>>(x, ws_A, lambda_fuse, tag_gate, out);
}

// Round 5
// 250.807 us; speedup vs baseline: 1.2236x; 1.0190x over previous
//
#include <hip/hip_runtime.h>
#include <math.h>

#define N_ 64
#define C_ 8
#define T_ 300
#define V_ 17
#define M_ 12
#define EPSF 1e-6f
#define TAUF 0.35f

typedef float f32x4 __attribute__((ext_vector_type(4)));

// x shape (N,C,T,V,M), strides: C:61200, T:204, V:12, M:1
// ws layout (floats): ws_part[64*10*48] per-(n,tchunk) partial sums
//                     (slot: pos d*12+m at [0,36), s at [36,48)) | ws_A[64*144]

#define TSPLIT 10
#define TCH (T_ / TSPLIT)   // 30 t per block

// ---------------- Kernel 1: partial reduce over a t-chunk -> private partial slot (no atomics on global)
__global__ __launch_bounds__(256) void k_reduce(const float* __restrict__ x,
                                                float* __restrict__ ws_part) {
    const int n = blockIdx.x;
    const int by = blockIdx.y;
    const int t0 = by * TCH;
    const int tid = threadIdx.x;
    __shared__ float pos_acc[36];
    __shared__ float s_acc[12];
    if (tid < 36) pos_acc[tid] = 0.f;
    if (tid < 12) s_acc[tid] = 0.f;
    __syncthreads();

    // ---- s part: channel 3, contiguous chunk of 30 rows = 6120 floats
    {
        const float* xs = x + ((size_t)(n * C_ + 3) * T_ + t0) * 204;
        float a0 = 0.f, a1 = 0.f, a2 = 0.f;
        for (int e = tid; e < TCH * 204; e += 768) {
            a0 += xs[e];
            if (e + 256 < TCH * 204) a1 += xs[e + 256];
            if (e + 512 < TCH * 204) a2 += xs[e + 512];
        }
        // chunk base divisible by 12; stride 768 ≡ 0 (mod 12): fixed m per phase
        int m0 = tid % 12;
        atomicAdd(&s_acc[m0], a0);
        atomicAdd(&s_acc[(m0 + 4) % 12], a1);
        atomicAdd(&s_acc[(m0 + 8) % 12], a2);
    }

    // ---- pos part: d in 0..2, t in chunk, 24 floats (v=11,12) per (d,t)
    for (int e = tid; e < 3 * TCH * 24; e += 256) {
        int d = e / (TCH * 24);
        int rem = e % (TCH * 24);
        int tt = rem / 24, j = rem % 24;
        float val = x[((size_t)(n * C_ + d) * T_ + t0 + tt) * 204 + 132 + j];
        atomicAdd(&pos_acc[d * 12 + (j % 12)], val);
    }
    __syncthreads();

    float* slot = ws_part + (size_t)(n * TSPLIT + by) * 48;
    if (tid < 36) slot[tid] = pos_acc[tid];
    if (tid < 12) slot[36 + tid] = s_acc[tid];
}

// ---------------- Kernel 2: sum partials, build fused adjacency A (N,12,12)
__global__ __launch_bounds__(64) void k_adj(const float* __restrict__ ws_part,
                                            const float* __restrict__ alpha_logits,
                                            float* __restrict__ ws_A) {
    const int n = blockIdx.x;
    const int tid = threadIdx.x;
    __shared__ float raw[48];
    __shared__ float posx[12], posy[12], posz[12];
    __shared__ float dist[144];
    __shared__ int ord[60];
    __shared__ float p_s[12];
    __shared__ float alpha_s[4];
    __shared__ float w_s;

    if (tid < 48) {
        float a = 0.f;
        #pragma unroll
        for (int j = 0; j < TSPLIT; ++j) a += ws_part[(size_t)(n * TSPLIT + j) * 48 + tid];
        raw[tid] = a;
    }
    __syncthreads();

    const float PSC = 0.5f / (float)T_;          // pos = raw * 0.5/T
    if (tid < 12) {
        posx[tid] = raw[0 * 12 + tid] * PSC;
        posy[tid] = raw[1 * 12 + tid] * PSC;
        posz[tid] = raw[2 * 12 + tid] * PSC;
    }
    if (tid == 0) {
        float l0 = alpha_logits[0], l1 = alpha_logits[1], l2 = alpha_logits[2], l3 = alpha_logits[3];
        float mx = fmaxf(fmaxf(l0, l1), fmaxf(l2, l3));
        float e0 = expf(l0 - mx), e1 = expf(l1 - mx), e2 = expf(l2 - mx), e3 = expf(l3 - mx);
        float s = e0 + e1 + e2 + e3;
        alpha_s[0] = e0 / s; alpha_s[1] = e1 / s; alpha_s[2] = e2 / s; alpha_s[3] = e3 / s;
    }
    if (tid == 1) {
        const float SSC = 1.f / ((float)(T_ * V_) * TAUF);  // s/tau = raw * SSC
        float sv[12];
        float mx = -1e30f;
        #pragma unroll
        for (int m = 0; m < 12; ++m) { sv[m] = raw[36 + m] * SSC; mx = fmaxf(mx, sv[m]); }
        float sum = 0.f;
        #pragma unroll
        for (int m = 0; m < 12; ++m) { sv[m] = expf(sv[m] - mx); sum += sv[m]; }
        float maxp = 0.f;
        #pragma unroll
        for (int m = 0; m < 12; ++m) { sv[m] = sv[m] / sum; p_s[m] = sv[m]; maxp = fmaxf(maxp, sv[m]); }
        float w = (maxp - 1.f / 12.f) / (1.f - 1.f / 12.f + EPSF);
        w_s = fminf(fmaxf(w, 0.f), 1.f);
    }
    __syncthreads();

    for (int e = tid; e < 144; e += 64) {
        int i = e / 12, j = e % 12;
        float dx = posx[i] - posx[j], dy = posy[i] - posy[j], dz = posz[i] - posz[j];
        dist[e] = sqrtf(dx * dx + dy * dy + dz * dz);
    }
    __syncthreads();

    // top-5 nearest per row (stable tie-break: smallest index wins, matches lax.top_k)
    if (tid < 12) {
        int i = tid, mask = 0;
        #pragma unroll
        for (int r = 0; r < 5; ++r) {
            float bd = 1e30f; int bj = -1;
            #pragma unroll
            for (int j = 0; j < 12; ++j) {
                if (!((mask >> j) & 1)) {
                    float dd = dist[i * 12 + j];
                    if (dd < bd) { bd = dd; bj = j; }
                }
            }
            ord[i * 5 + r] = bj; mask |= (1 << bj);
        }
    }
    __syncthreads();

    float w = w_s;
    for (int e = tid; e < 144; e += 64) {
        int i = e / 12, j = e % 12;
        int rank = 5;
        #pragma unroll
        for (int r = 4; r >= 0; --r) if (ord[i * 5 + r] == j) rank = r;
        float diag = (i == j) ? 1.f : 0.f;
        // kNN rows always contain self (dist 0) -> row sum == k+1 exactly
        float aknn = 0.f;
        #pragma unroll
        for (int kk = 0; kk < 4; ++kk) {
            int K = kk + 2;
            float val = ((rank < K) ? 1.f : 0.f) + diag;
            aknn += alpha_s[kk] * val / ((float)(K + 1) + EPSF);
        }
        float pi = p_s[i], pj = p_s[j];
        float di = 12.f * pi + 2.f, dj = 12.f * pj + 2.f;  // ball row sums
        float ab = (pi + pj + diag) * rsqrtf(di + EPSF) * rsqrtf(dj + EPSF);
        ws_A[n * 144 + e] = w * ab + (1.f - w) * aknn;
    }
}

// ---------------- Kernel 3: out = x + scale * (A@root - root), single coalesced read via LDS
#define RT 30   // rows (c,t) per block; 2400 % 30 == 0
__global__ __launch_bounds__(256) void k_main(const float* __restrict__ x,
                                              const float* __restrict__ ws_A,
                                              const float* __restrict__ lambda_fuse,
                                              const float* __restrict__ tag_gate,
                                              float* __restrict__ out) {
    const int n = blockIdx.y;
    const int r0 = blockIdx.x * RT;   // row index within n, rows = C*T = 2400
    const int tid = threadIdx.x;
    __shared__ f32x4 xs4[RT * 51];    // 30 rows x 204 floats = 24480 B, float4-aligned
    __shared__ float Ash[144];
    __shared__ float root_sh[RT * 12];
    __shared__ float delta_sh[RT * 12];
    float* xs = (float*)xs4;

    if (tid < 144) Ash[tid] = ws_A[n * 144 + tid];
    float scale = tanhf(tag_gate[0]) * lambda_fuse[0];

    const float* xn = x + (size_t)n * 2400 * 204;
    float* on = out + (size_t)n * 2400 * 204;
    const f32x4* x4 = (const f32x4*)(xn + (size_t)r0 * 204);  // r0*204 % 4 == 0
    f32x4* o4 = (f32x4*)(on + (size_t)r0 * 204);

    // Phase A: coalesced single read of the whole tile into LDS
    for (int f = tid; f < RT * 51; f += 256) xs4[f] = x4[f];
    __syncthreads();

    // Phase B1: root from LDS
    for (int e = tid; e < RT * 12; e += 256) {
        int r = e / 12, v = e % 12;
        root_sh[e] = 0.5f * (xs[r * 204 + 132 + v] + xs[r * 204 + 144 + v]);  // v=11,12
    }
    __syncthreads();
    // Phase B2: delta = scale * (A@root - root)
    for (int e = tid; e < RT * 12; e += 256) {
        int r = e / 12, u = e % 12;
        float acc = 0.f;
        #pragma unroll
        for (int v = 0; v < 12; ++v) acc += Ash[u * 12 + v] * root_sh[r * 12 + v];
        delta_sh[e] = scale * (acc - root_sh[e]);
    }
    __syncthreads();

    // Phase C: out = lds + delta, nontemporal coalesced store
    for (int f = tid; f < RT * 51; f += 256) {
        int r = f / 51, j = f % 51;
        int m0 = (4 * j) % 12;            // m never wraps inside a float4 (m0 in {0,4,8})
        f32x4 v = xs4[f];
        const float* d = &delta_sh[r * 12 + m0];
        v.x += d[0]; v.y += d[1]; v.z += d[2]; v.w += d[3];
        __builtin_nontemporal_store(v, &o4[f]);
    }
}

extern "C" void kernel_launch(void* const* d_in, const int* in_sizes, int n_in,
                              void* d_out, int out_size, void* d_ws, size_t ws_size,
                              hipStream_t stream) {
    const float* x = (const float*)d_in[0];
    const float* alpha_logits = (const float*)d_in[1];
    const float* lambda_fuse = (const float*)d_in[2];
    const float* tag_gate = (const float*)d_in[3];
    float* out = (float*)d_out;

    float* ws = (float*)d_ws;
    float* ws_part = ws;                      // 64*10*48 floats
    float* ws_A = ws + 64 * TSPLIT * 48;      // 64*144

    k_reduce<<<dim3(N_, TSPLIT), dim3(256), 0, stream>>>(x, ws_part);
    k_adj<<<dim3(N_), dim3(64), 0, stream>>>(ws_part, alpha_logits, ws_A);
    k_main<<<dim3(2400 / RT, N_), dim3(256), 0, stream>>>(x, ws_A, lambda_fuse, tag_gate, out);
}